// Round 7
// baseline (1922.112 us; speedup 1.0000x reference)
//
#include <hip/hip_runtime.h>
#include <math.h>

// Problem constants
#define DMODEL 256
#define NHEADS 8
#define NLAY 6
#define DFF 1024
#define DHEAD 32
#define NB 2
#define STOT 21760
#define MTOT (NB * STOT)   // 43520 = 128 * 340

typedef unsigned short u16;
typedef __attribute__((ext_vector_type(8))) short short8;
typedef __attribute__((ext_vector_type(4))) float floatx4;
typedef __attribute__((ext_vector_type(2))) float float2v;

__device__ __forceinline__ float bf2f(u16 h) {
    unsigned int u = ((unsigned int)h) << 16;
    return __uint_as_float(u);
}
__device__ __forceinline__ u16 f2bf(float f) {
    unsigned int u = __float_as_uint(f);
    u = u + 0x7fffu + ((u >> 16) & 1u);   // RNE
    return (u16)(u >> 16);
}

// packed dual-FMA: acc = a * b + acc (2 f32 lanes per instruction)
__device__ __forceinline__ void pkfma(float2v& acc, float2v a, float2v b) {
    asm("v_pk_fma_f32 %0, %1, %2, %0" : "+v"(acc) : "v"(a), "v"(b));
}
// packed bf16 pair (one uint) -> packed f32 pair
__device__ __forceinline__ float2v unpk(unsigned int u) {
    float2v r;
    r.x = __uint_as_float(u << 16);
    r.y = __uint_as_float(u & 0xffff0000u);
    return r;
}

// async global->LDS, 16B per lane. lds dest must be wave-uniform base
// (HW adds lane*16); global src is per-lane.
__device__ __forceinline__ void gload16(const u16* g, u16* l) {
    __builtin_amdgcn_global_load_lds(
        (const __attribute__((address_space(1))) unsigned int*)(g),
        (__attribute__((address_space(3))) unsigned int*)(l),
        16, 0, 0);
}

// ---------------------------------------------------------------------------
// Concatenated bias [NLAY][384] = boff[i] (256) || battn[i] (128)
// ---------------------------------------------------------------------------
__global__ __launch_bounds__(256)
void biascat_kernel(const float* __restrict__ boff, const float* __restrict__ battn,
                    float* __restrict__ bias384)
{
    const int t = blockIdx.x * 256 + threadIdx.x;
    if (t >= NLAY * 384) return;
    const int i = t / 384, c = t - i * 384;
    bias384[t] = (c < 256) ? boff[i * 256 + c] : battn[i * 128 + (c - 256)];
}

// ---------------------------------------------------------------------------
// Weight transpose + bf16 cast: W[K,N] f32 -> Wt[N,K] bf16.
// ---------------------------------------------------------------------------
__global__ __launch_bounds__(256)
void wtrans_kernel(const float* __restrict__ W, u16* __restrict__ Wt,
                   const int K, const int N, const long wstride, const long ostride)
{
    __shared__ float ts[32][33];
    W  += blockIdx.z * wstride;
    Wt += blockIdx.z * ostride;
    const int n0 = blockIdx.x * 32;
    const int k0 = blockIdx.y * 32;
    const int t = threadIdx.x;
    const int nl = t & 31, kl = t >> 5;        // kl 0..7
#pragma unroll
    for (int p = 0; p < 4; ++p) {
        const int k = kl + p * 8;
        ts[k][nl] = W[(long)(k0 + k) * N + n0 + nl];
    }
    __syncthreads();
    const int c = t & 31, r0 = t >> 5;
#pragma unroll
    for (int p = 0; p < 4; ++p) {
        const int r = r0 + p * 8;
        Wt[(long)(n0 + r) * K + k0 + c] = f2bf(ts[c][r]);
    }
}

// ---------------------------------------------------------------------------
// Flatten: src[b,d,y,x] -> out f32, outb bf16, posb bf16, qb = bf16(src+pos+le)
// ---------------------------------------------------------------------------
__global__ __launch_bounds__(256)
void flatten_kernel(const float* __restrict__ src, const float* __restrict__ pos,
                    const float* __restrict__ le_row,
                    float* __restrict__ out, u16* __restrict__ outb,
                    u16* __restrict__ posb, u16* __restrict__ qb,
                    int HW, int start)
{
    __shared__ float ts[32][33];
    __shared__ float tp[32][33];
    const int b   = blockIdx.z;
    const int d0  = blockIdx.y * 32;
    const int hw0 = blockIdx.x * 32;
    const int t   = threadIdx.x;
    const int hwl = t & 31;
    const int dl  = t >> 5;
#pragma unroll
    for (int p = 0; p < 4; ++p) {
        const int dd = dl + p * 8;
        const int d  = d0 + dd;
        const long idx = ((long)(b * DMODEL + d)) * HW + hw0 + hwl;
        ts[dd][hwl] = src[idx];
        tp[dd][hwl] = pos[idx] + le_row[d];
    }
    __syncthreads();
    const int dl2  = t & 31;
    const int hwl2 = t >> 5;
#pragma unroll
    for (int p = 0; p < 4; ++p) {
        const int hh  = hwl2 + p * 8;
        const int tok = start + hw0 + hh;
        const long o  = ((long)(b * STOT + tok)) * DMODEL + d0 + dl2;
        const float v = ts[dl2][hh];
        const float pp = tp[dl2][hh];
        out[o]  = v;
        outb[o] = f2bf(v);
        posb[o] = f2bf(pp);
        qb[o]   = f2bf(v + pp);
    }
}

// ---------------------------------------------------------------------------
// bf16 MFMA GEMM: Cb[M,N]bf16 = A[M,K]bf16 @ Bt[N,K]bf16^T + bias (relu opt)
// 3-stage global_load_lds pipeline with COUNTED vmcnt + raw s_barrier:
// tile k's loads are waited with vmcnt(4) (tile k+1 stays in flight across
// the barrier), tile k+2 is issued under tile k's compute. lgkmcnt(0) before
// the barrier makes the buffer-overwrite safe (all ds_reads of the buffer
// being re-staged have completed in every wave).
// Optional second problem fused along grid.x (block-uniform pointer select).
// ---------------------------------------------------------------------------
__global__ __launch_bounds__(256)
void mfma_gemm(const u16* __restrict__ A, const u16* __restrict__ Bt,
               const int ldb, const float* __restrict__ bias,
               u16* __restrict__ Cb, const int ldc, u16* __restrict__ Cb2,
               const int K, const int relu,
               const u16* __restrict__ A1, const u16* __restrict__ Bt1,
               const float* __restrict__ bias1, u16* __restrict__ Cb1,
               u16* __restrict__ Cb21, const int nsplit)
{
    __shared__ u16 As[3][128 * 32];
    __shared__ u16 Bs[3][128 * 32];
    int bx = blockIdx.x;
    if (A1 && bx >= nsplit) {
        A = A1; Bt = Bt1; bias = bias1; Cb = Cb1; Cb2 = Cb21; bx -= nsplit;
    }
    const int tid  = threadIdx.x;
    const int wv   = tid >> 6;
    const int lane = tid & 63;
    const int m0 = blockIdx.y * 128;
    const int n0 = bx * 128;
    const int wm = (wv & 1) * 64;
    const int wn = (wv >> 1) * 64;
    const int q   = lane >> 4;
    const int c16 = lane & 15;

    // staging: chunk = it*4 + wv covers rows [chunk*16, chunk*16+16)
    const int lrow = lane >> 2;
    const int lcol = (lane & 3) * 8;   // u16 units

    const u16* ag[2];
    const u16* bg[2];
#pragma unroll
    for (int it = 0; it < 2; ++it) {
        const int chunk = it * 4 + wv;
        const int row = chunk * 16 + lrow;
        ag[it] = A  + (long)(m0 + row) * K   + lcol;
        bg[it] = Bt + (long)(n0 + row) * ldb + lcol;
    }

#define STAGE(buf, kk)                                          \
    {                                                           \
        _Pragma("unroll")                                       \
        for (int it = 0; it < 2; ++it) {                        \
            const int chunk = it * 4 + wv;                      \
            gload16(ag[it] + (kk), &As[buf][chunk * 512]);      \
            gload16(bg[it] + (kk), &Bs[buf][chunk * 512]);      \
        }                                                       \
    }

    floatx4 acc[4][4];
#pragma unroll
    for (int i = 0; i < 4; ++i)
#pragma unroll
        for (int j = 0; j < 4; ++j)
            acc[i][j] = (floatx4){0.f, 0.f, 0.f, 0.f};

    const int nk = K >> 5;          // >= 8 always here
    STAGE(0, 0);
    STAGE(1, 32);

    int cur = 0;
    for (int k = 0; k < nk; ++k) {
        __builtin_amdgcn_sched_barrier(0);
        if (k < nk - 1) {
            // wait tile k only; tile k+1's 4 loads stay in flight
            asm volatile("s_waitcnt vmcnt(4) lgkmcnt(0)" ::: "memory");
        } else {
            asm volatile("s_waitcnt vmcnt(0) lgkmcnt(0)" ::: "memory");
        }
        __builtin_amdgcn_s_barrier();
        __builtin_amdgcn_sched_barrier(0);

        if (k + 2 < nk) {
            const int nb = (cur + 2 >= 3) ? (cur - 1) : (cur + 2);
            STAGE(nb, (k + 2) * 32);
        }

        const u16* Ab = &As[cur][0];
        const u16* Bb = &Bs[cur][0];
        short8 af[4], bf[4];
#pragma unroll
        for (int i = 0; i < 4; ++i) {
            af[i] = *(const short8*)&Ab[(wm + i * 16 + c16) * 32 + q * 8];
            bf[i] = *(const short8*)&Bb[(wn + i * 16 + c16) * 32 + q * 8];
        }
#pragma unroll
        for (int i = 0; i < 4; ++i)
#pragma unroll
            for (int j = 0; j < 4; ++j)
                acc[i][j] = __builtin_amdgcn_mfma_f32_16x16x32_bf16(
                    af[i], bf[j], acc[i][j], 0, 0, 0);

        cur = (cur == 2) ? 0 : (cur + 1);
    }
#undef STAGE

    // output selection (block-uniform)
    u16* cb  = Cb;
    int ldcb = ldc, csub = 0;
    if (Cb2 && n0 >= 256) { cb = Cb2; ldcb = 128; csub = 256; }

#pragma unroll
    for (int i = 0; i < 4; ++i) {
#pragma unroll
        for (int j = 0; j < 4; ++j) {
            const int col = n0 + wn + j * 16 + c16;
            const float bv = bias ? bias[col] : 0.f;
#pragma unroll
            for (int r = 0; r < 4; ++r) {
                const int row = m0 + wm + i * 16 + q * 4 + r;
                float v = acc[i][j][r] + bv;
                if (relu) v = fmaxf(v, 0.f);
                cb[(long)row * ldcb + col - csub] = f2bf(v);
            }
        }
    }
}

// ---------------------------------------------------------------------------
// Deformable sampling — hybrid decomposition, LDS-broadcast (w,o) table
// (R5 body: best measured config — occupancy-first, compiler-scheduled).
// ---------------------------------------------------------------------------
__device__ __forceinline__ void point_corners(
    float refx, float refy, unsigned int o2, float aP,
    int k, unsigned int base, float* w, unsigned int* o)
{
    const int lw = 128 >> k;
    const float flw = (float)lw;
    const float x = refx * flw - 0.5f + bf2f((u16)(o2 & 0xffffu));
    const float y = refy * flw - 0.5f + bf2f((u16)(o2 >> 16));
    const float x0f = floorf(x), y0f = floorf(y);
    const float lx = x - x0f, ly = y - y0f;
    const int x0 = (int)x0f, y0 = (int)y0f;
    const float wx0 = ((unsigned int)x0 < (unsigned int)lw) ? (1.f - lx) : 0.f;
    const float wx1 = ((unsigned int)(x0 + 1) < (unsigned int)lw) ? lx : 0.f;
    const float wy0 = ((unsigned int)y0 < (unsigned int)lw) ? (aP * (1.f - ly)) : 0.f;
    const float wy1 = ((unsigned int)(y0 + 1) < (unsigned int)lw) ? (aP * ly) : 0.f;
    // byte offsets: token stride 512B; row stride lw*512 = 1<<(16-k)
    const unsigned int xc0 = (unsigned int)(x0 & (lw - 1)) << 9;
    const unsigned int xc1 = (unsigned int)((x0 + 1) & (lw - 1)) << 9;
    const unsigned int r0 = (unsigned int)(y0 & (lw - 1)) << (16 - k);
    const unsigned int r1 = (unsigned int)((y0 + 1) & (lw - 1)) << (16 - k);
    w[0] = wy0 * wx0; o[0] = base + r0 + xc0;
    w[1] = wy0 * wx1; o[1] = base + r0 + xc1;
    w[2] = wy1 * wx0; o[2] = base + r1 + xc0;
    w[3] = wy1 * wx1; o[3] = base + r1 + xc1;
}

__global__ __launch_bounds__(256, 4)
void sample_kernel(const u16* __restrict__ value, const u16* __restrict__ offb,
                   const u16* __restrict__ logit, u16* __restrict__ sb)
{
    // per wave: 8 heads x 132 uints (512B payload + 16B pad) = 4224B
    __shared__ unsigned int pwtab[4 * 8 * 132];

    const int t  = threadIdx.x;
    const int wv = t >> 6;                 // token slot within block
    const int l  = t & 63;
    const int h  = l >> 3;                 // head 0..7
    const int u  = l & 7;                  // point-pair owner / channel slice
    const int blk = blockIdx.x * 4 + wv;   // global token
    const int b = blk / STOT;
    const int s = blk - b * STOT;

    float refx, refy;
    if (s < 16384) {
        const int yy = s >> 7, xx = s & 127;
        refx = (xx + 0.5f) * (1.f / 128.f); refy = (yy + 0.5f) * (1.f / 128.f);
    } else if (s < 20480) {
        const int sl = s - 16384; const int yy = sl >> 6, xx = sl & 63;
        refx = (xx + 0.5f) * (1.f / 64.f);  refy = (yy + 0.5f) * (1.f / 64.f);
    } else if (s < 21504) {
        const int sl = s - 20480; const int yy = sl >> 5, xx = sl & 31;
        refx = (xx + 0.5f) * (1.f / 32.f);  refy = (yy + 0.5f) * (1.f / 32.f);
    } else {
        const int sl = s - 21504; const int yy = sl >> 4, xx = sl & 15;
        refx = (xx + 0.5f) * (1.f / 16.f);  refy = (yy + 0.5f) * (1.f / 16.f);
    }

    // ---- phase 1: this lane's 2 points ----
    const unsigned int* offp = (const unsigned int*)(offb + (long)blk * 256 + h * 32);
    const unsigned int o2_0 = offp[u];
    const unsigned int o2_1 = offp[u + 8];
    const u16* lp = logit + (long)blk * 128 + h * 16;
    const float l0 = bf2f(lp[u]);
    const float l1 = bf2f(lp[u + 8]);

    // softmax across the head's 8 lanes (16 logits)
    float m = fmaxf(l0, l1);
    m = fmaxf(m, __shfl_xor(m, 1));
    m = fmaxf(m, __shfl_xor(m, 2));
    m = fmaxf(m, __shfl_xor(m, 4));
    const float e0 = __expf(l0 - m);
    const float e1 = __expf(l1 - m);
    float se = e0 + e1;
    se += __shfl_xor(se, 1);
    se += __shfl_xor(se, 2);
    se += __shfl_xor(se, 4);
    const float inv = 1.f / se;
    const float aP0 = e0 * inv;
    const float aP1 = e1 * inv;

    // levels: point u -> level u>>2 (0/1), point u+8 -> level (u>>2)+2 (2/3)
    const int k0 = u >> 2;
    const unsigned int LS0 = k0 ? 16384u : 0u;
    const unsigned int LS1 = k0 ? 21504u : 20480u;
    const unsigned int tb = (unsigned int)(b * STOT);
    const unsigned int hb64 = (unsigned int)(h * 64);
    const unsigned int base0 = (tb + LS0) * 512u + hb64;
    const unsigned int base1 = (tb + LS1) * 512u + hb64;

    float ww[8];
    unsigned int oo[8];
    point_corners(refx, refy, o2_0, aP0, k0,     base0, ww,     oo);
    point_corners(refx, refy, o2_1, aP1, k0 + 2, base1, ww + 4, oo + 4);

    // ---- publish (w,o) pairs to the per-head LDS table ----
    unsigned int* wbase = pwtab + (wv * 8 + h) * 132;
    {
        uint4 p0, p1, p2, p3;
        p0.x = __float_as_uint(ww[0]); p0.y = oo[0];
        p0.z = __float_as_uint(ww[1]); p0.w = oo[1];
        p1.x = __float_as_uint(ww[2]); p1.y = oo[2];
        p1.z = __float_as_uint(ww[3]); p1.w = oo[3];
        p2.x = __float_as_uint(ww[4]); p2.y = oo[4];
        p2.z = __float_as_uint(ww[5]); p2.w = oo[5];
        p3.x = __float_as_uint(ww[6]); p3.y = oo[6];
        p3.z = __float_as_uint(ww[7]); p3.w = oo[7];
        *(uint4*)(wbase + u * 8)           = p0;
        *(uint4*)(wbase + u * 8 + 4)       = p1;
        *(uint4*)(wbase + (u + 8) * 8)     = p2;
        *(uint4*)(wbase + (u + 8) * 8 + 4) = p3;
    }
    __builtin_amdgcn_wave_barrier();   // same-wave producer/consumer only

    // ---- phase 2: coalesced gathers, 4 points per batch ----
    const unsigned int chb = (unsigned int)(u * 8);  // channel byte offset
    const char* vp = (const char*)value;
    float2v acc0; acc0.x = 0.f; acc0.y = 0.f;
    float2v acc1; acc1.x = 0.f; acc1.y = 0.f;

#pragma unroll
    for (int g = 0; g < 4; ++g) {
        const uint4* gp = (const uint4*)(wbase + g * 32);
        uint4 qq[8];
#pragma unroll
        for (int i = 0; i < 8; ++i) qq[i] = gp[i];
        uint2 dB[16];
#pragma unroll
        for (int i = 0; i < 8; ++i) {
            dB[2 * i]     = *(const uint2*)(vp + (qq[i].y + chb));
            dB[2 * i + 1] = *(const uint2*)(vp + (qq[i].w + chb));
        }
#pragma unroll
        for (int i = 0; i < 8; ++i) {
            float2v wa; wa.x = __uint_as_float(qq[i].x); wa.y = wa.x;
            pkfma(acc0, wa, unpk(dB[2 * i].x));
            pkfma(acc1, wa, unpk(dB[2 * i].y));
            float2v wb; wb.x = __uint_as_float(qq[i].z); wb.y = wb.x;
            pkfma(acc0, wb, unpk(dB[2 * i + 1].x));
            pkfma(acc1, wb, unpk(dB[2 * i + 1].y));
        }
    }

    ushort4 r;
    r.x = f2bf(acc0.x); r.y = f2bf(acc0.y);
    r.z = f2bf(acc1.x); r.w = f2bf(acc1.y);
    *(ushort4*)(sb + (long)blk * DMODEL + h * 32 + u * 4) = r;
}

// ---------------------------------------------------------------------------
// out = LayerNorm(out + delta_bf16); writes f32 residual + bf16 outb.
// If qb != null: also writes qb = bf16(LNout + posb) for next layer's q-GEMM.
// ---------------------------------------------------------------------------
__global__ __launch_bounds__(256)
void ln_kernel(float* __restrict__ out, u16* __restrict__ outb,
               u16* __restrict__ qb, const u16* __restrict__ posb,
               const u16* __restrict__ db,
               const float* __restrict__ gamma, const float* __restrict__ beta)
{
    const int wave = threadIdx.x >> 6;
    const int lane = threadIdx.x & 63;
    const long tok = (long)blockIdx.x * 4 + wave;
    float* op = out + tok * DMODEL + lane * 4;
    const float4 xo = *(const float4*)op;
    const ushort4 d4 = *(const ushort4*)(db + tok * DMODEL + lane * 4);
    float x[4] = {xo.x + bf2f(d4.x), xo.y + bf2f(d4.y),
                  xo.z + bf2f(d4.z), xo.w + bf2f(d4.w)};

    float sum = x[0] + x[1] + x[2] + x[3];
#pragma unroll
    for (int o = 32; o >= 1; o >>= 1) sum += __shfl_xor(sum, o);
    const float mean = sum * (1.f / 256.f);

    float vs = 0.f;
#pragma unroll
    for (int i = 0; i < 4; ++i) { const float d2 = x[i] - mean; vs += d2 * d2; }
#pragma unroll
    for (int o = 32; o >= 1; o >>= 1) vs += __shfl_xor(vs, o);
    const float rstd = rsqrtf(vs * (1.f / 256.f) + 1e-5f);

    const float4 g  = *(const float4*)(gamma + lane * 4);
    const float4 be = *(const float4*)(beta + lane * 4);
    float r[4];
    r[0] = (x[0] - mean) * rstd * g.x + be.x;
    r[1] = (x[1] - mean) * rstd * g.y + be.y;
    r[2] = (x[2] - mean) * rstd * g.z + be.z;
    r[3] = (x[3] - mean) * rstd * g.w + be.w;
    float4 rf; rf.x = r[0]; rf.y = r[1]; rf.z = r[2]; rf.w = r[3];
    *(float4*)op = rf;
    ushort4 rb;
    rb.x = f2bf(r[0]); rb.y = f2bf(r[1]); rb.z = f2bf(r[2]); rb.w = f2bf(r[3]);
    *(ushort4*)(outb + tok * DMODEL + lane * 4) = rb;
    if (qb) {
        const ushort4 p4 = *(const ushort4*)(posb + tok * DMODEL + lane * 4);
        ushort4 qv;
        qv.x = f2bf(r[0] + bf2f(p4.x));
        qv.y = f2bf(r[1] + bf2f(p4.y));
        qv.z = f2bf(r[2] + bf2f(p4.z));
        qv.w = f2bf(r[3] + bf2f(p4.w));
        *(ushort4*)(qb + tok * DMODEL + lane * 4) = qv;
    }
}

// ---------------------------------------------------------------------------
extern "C" void kernel_launch(void* const* d_in, const int* in_sizes, int n_in,
                              void* d_out, int out_size, void* d_ws, size_t ws_size,
                              hipStream_t stream)
{
    const float* src[4] = {(const float*)d_in[0], (const float*)d_in[2],
                           (const float*)d_in[4], (const float*)d_in[6]};
    const float* pos[4] = {(const float*)d_in[1], (const float*)d_in[3],
                           (const float*)d_in[5], (const float*)d_in[7]};
    const float* level_embed = (const float*)d_in[8];
    const float* Woff  = (const float*)d_in[9];
    const float* boff  = (const float*)d_in[10];
    const float* Wattn = (const float*)d_in[11];
    const float* battn = (const float*)d_in[12];
    const float* Wval  = (const float*)d_in[13];
    const float* bval  = (const float*)d_in[14];
    const float* Wout  = (const float*)d_in[15];
    const float* bout  = (const float*)d_in[16];
    const float* ln1s  = (const float*)d_in[17];
    const float* ln1b  = (const float*)d_in[18];
    const float* W1    = (const float*)d_in[19];
    const float* b1    = (const float*)d_in[20];
    const float* W2    = (const float*)d_in[21];
    const float* b2    = (const float*)d_in[22];
    const float* ln2s  = (const float*)d_in[23];
    const float* ln2b  = (const float*)d_in[24];

    float* out = (float*)d_out;                       // residual stream f32
    const long MD = (long)MTOT * DMODEL;              // 11,141,120

    // workspace layout (~187 MB)
    u16* outb = (u16*)d_ws;          // [M,256] LN output bf16
    u16* posb = outb + MD;           // [M,256] pos_flat bf16
    u16* qb   = posb + MD;           // [M,256] q = out+pos bf16
    u16* db   = qb + MD;             // [M,256] delta bf16 (attn_out / ff_out)
    u16* vb   = db + MD;             // [M,256] value bf16      (hb region start)
    u16* offb = vb + MD;             // [M,256] offsets bf16
    u16* awb  = offb + MD;           // [M,128] attn logits bf16
    u16* sb   = awb + MD / 2;        // [M,256] sampled bf16
    u16* hb   = vb;                  // [M,1024] FF hidden (aliases vb..sb+pad)
    u16* wts  = vb + 4 * MD;         // bf16 transposed weights
    u16* Wvalt = wts;
    u16* Wofat = Wvalt + 6L * 256 * 256;   // [384,256] per layer: Woff^T||Wattn^T
    u16* Woutt = Wofat + 6L * 384 * 256;
    u16* W1t   = Woutt + 6L * 256 * 256;
    u16* W2t   = W1t   + 6L * 1024 * 256;
    float* bias384 = (float*)(W2t + 6L * 1024 * 256);  // [NLAY][384]

    // ---- weight prep (every call; ~9 MB) ----
    biascat_kernel<<<9, 256, 0, stream>>>(boff, battn, bias384);
    wtrans_kernel<<<dim3(8, 8, 6),  256, 0, stream>>>(Wval,  Wvalt, 256, 256,
                                                      65536, 65536);
    wtrans_kernel<<<dim3(8, 8, 6),  256, 0, stream>>>(Woff,  Wofat, 256, 256,
                                                      65536, 98304);
    wtrans_kernel<<<dim3(4, 8, 6),  256, 0, stream>>>(Wattn, Wofat + 256 * 256,
                                                      256, 128, 32768, 98304);
    wtrans_kernel<<<dim3(8, 8, 6),  256, 0, stream>>>(Wout,  Woutt, 256, 256,
                                                      65536, 65536);
    wtrans_kernel<<<dim3(32, 8, 6), 256, 0, stream>>>(W1,    W1t, 256, 1024,
                                                      262144, 262144);
    wtrans_kernel<<<dim3(8, 32, 6), 256, 0, stream>>>(W2,    W2t, 1024, 256,
                                                      262144, 262144);

    // ---- flatten ----
    {
        const int HW[4] = {16384, 4096, 1024, 256};
        const int ST[4] = {0, 16384, 20480, 21504};
        for (int l = 0; l < 4; ++l) {
            dim3 g(HW[l] / 32, DMODEL / 32, NB);
            flatten_kernel<<<g, 256, 0, stream>>>(src[l], pos[l],
                                                  level_embed + l * DMODEL,
                                                  out, outb, posb, qb, HW[l], ST[l]);
        }
    }

    const dim3 g2(2, MTOT / 128);   // N=256
    const dim3 g5(5, MTOT / 128);   // merged value (2) + off/attn (3)
    const dim3 g8(8, MTOT / 128);   // N=1024 (FF1)

    for (int i = 0; i < NLAY; ++i) {
        const u16* Wv  = Wvalt + (long)i * 256 * 256;
        const u16* Wqa = Wofat + (long)i * 384 * 256;
        const u16* Wou = Woutt + (long)i * 256 * 256;
        const u16* W1i = W1t   + (long)i * 1024 * 256;
        const u16* W2i = W2t   + (long)i * 256 * 1024;
        const float* bv  = bval + (long)i * 256;
        const float* bqa = bias384 + (long)i * 384;
        const float* bou = bout + (long)i * 256;
        const float* b1i = b1   + (long)i * DFF;
        const float* b2i = b2   + (long)i * 256;

        // merged: value = outb @ Wval + bval -> vb  (blocks 0..1)
        //         [off|attn] = qb @ Wqa + bqa -> offb/awb (blocks 2..4)
        mfma_gemm<<<g5, 256, 0, stream>>>(outb, Wv, 256, bv,
                                          vb, 256, nullptr, 256, 0,
                                          qb, Wqa, bqa, offb, awb, 2);
        // sampling with fused softmax (reads logits directly)
        sample_kernel<<<MTOT / 4, 256, 0, stream>>>(vb, offb, awb, sb);
        // attn_out = s @ Wout + bout -> db bf16
        mfma_gemm<<<g2, 256, 0, stream>>>(sb, Wou, 256, bou,
                                          db, 256, nullptr, 256, 0,
                                          nullptr, nullptr, nullptr, nullptr,
                                          nullptr, 0);
        ln_kernel<<<MTOT / 4, 256, 0, stream>>>(out, outb, nullptr, nullptr, db,
                                                ln1s + (long)i * 256,
                                                ln1b + (long)i * 256);
        // FF: h = relu(out @ W1 + b1) -> hb bf16 [M,1024]
        mfma_gemm<<<g8, 256, 0, stream>>>(outb, W1i, 256, b1i,
                                          hb, 1024, nullptr, 256, 1,
                                          nullptr, nullptr, nullptr, nullptr,
                                          nullptr, 0);
        // ff_out = h @ W2 + b2 -> db bf16
        mfma_gemm<<<g2, 256, 0, stream>>>(hb, W2i, 1024, b2i,
                                          db, 256, nullptr, 1024, 0,
                                          nullptr, nullptr, nullptr, nullptr,
                                          nullptr, 0);
        ln_kernel<<<MTOT / 4, 256, 0, stream>>>(out, outb, qb, posb, db,
                                                ln2s + (long)i * 256,
                                                ln2b + (long)i * 256);
    }
}

// Round 8
// 1832.551 us; speedup vs baseline: 1.0489x; 1.0489x over previous
//
#include <hip/hip_runtime.h>
#include <math.h>

// Problem constants
#define DMODEL 256
#define NHEADS 8
#define NLAY 6
#define DFF 1024
#define DHEAD 32
#define NB 2
#define STOT 21760
#define MTOT (NB * STOT)   // 43520 = 128 * 340

typedef unsigned short u16;
typedef __attribute__((ext_vector_type(8))) short short8;
typedef __attribute__((ext_vector_type(4))) float floatx4;
typedef __attribute__((ext_vector_type(2))) float float2v;

__device__ __forceinline__ float bf2f(u16 h) {
    unsigned int u = ((unsigned int)h) << 16;
    return __uint_as_float(u);
}
__device__ __forceinline__ u16 f2bf(float f) {
    unsigned int u = __float_as_uint(f);
    u = u + 0x7fffu + ((u >> 16) & 1u);   // RNE
    return (u16)(u >> 16);
}

// packed dual-FMA: acc = a * b + acc (2 f32 lanes per instruction)
__device__ __forceinline__ void pkfma(float2v& acc, float2v a, float2v b) {
    asm("v_pk_fma_f32 %0, %1, %2, %0" : "+v"(acc) : "v"(a), "v"(b));
}
// packed bf16 pair (one uint) -> packed f32 pair
__device__ __forceinline__ float2v unpk(unsigned int u) {
    float2v r;
    r.x = __uint_as_float(u << 16);
    r.y = __uint_as_float(u & 0xffff0000u);
    return r;
}

// async global->LDS, 16B per lane. lds dest must be wave-uniform base
// (HW adds lane*16); global src is per-lane.
__device__ __forceinline__ void gload16(const u16* g, u16* l) {
    __builtin_amdgcn_global_load_lds(
        (const __attribute__((address_space(1))) unsigned int*)(g),
        (__attribute__((address_space(3))) unsigned int*)(l),
        16, 0, 0);
}

// ---------------------------------------------------------------------------
// Concatenated bias [NLAY][384] = boff[i] (256) || battn[i] (128)
// ---------------------------------------------------------------------------
__global__ __launch_bounds__(256)
void biascat_kernel(const float* __restrict__ boff, const float* __restrict__ battn,
                    float* __restrict__ bias384)
{
    const int t = blockIdx.x * 256 + threadIdx.x;
    if (t >= NLAY * 384) return;
    const int i = t / 384, c = t - i * 384;
    bias384[t] = (c < 256) ? boff[i * 256 + c] : battn[i * 128 + (c - 256)];
}

// ---------------------------------------------------------------------------
// Weight transpose + bf16 cast: W[K,N] f32 -> Wt[N,K] bf16.
// ---------------------------------------------------------------------------
__global__ __launch_bounds__(256)
void wtrans_kernel(const float* __restrict__ W, u16* __restrict__ Wt,
                   const int K, const int N, const long wstride, const long ostride)
{
    __shared__ float ts[32][33];
    W  += blockIdx.z * wstride;
    Wt += blockIdx.z * ostride;
    const int n0 = blockIdx.x * 32;
    const int k0 = blockIdx.y * 32;
    const int t = threadIdx.x;
    const int nl = t & 31, kl = t >> 5;        // kl 0..7
#pragma unroll
    for (int p = 0; p < 4; ++p) {
        const int k = kl + p * 8;
        ts[k][nl] = W[(long)(k0 + k) * N + n0 + nl];
    }
    __syncthreads();
    const int c = t & 31, r0 = t >> 5;
#pragma unroll
    for (int p = 0; p < 4; ++p) {
        const int r = r0 + p * 8;
        Wt[(long)(n0 + r) * K + k0 + c] = f2bf(ts[c][r]);
    }
}

// ---------------------------------------------------------------------------
// Flatten: src[b,d,y,x] -> out f32, outb bf16, posb bf16, qb = bf16(src+pos+le)
// ---------------------------------------------------------------------------
__global__ __launch_bounds__(256)
void flatten_kernel(const float* __restrict__ src, const float* __restrict__ pos,
                    const float* __restrict__ le_row,
                    float* __restrict__ out, u16* __restrict__ outb,
                    u16* __restrict__ posb, u16* __restrict__ qb,
                    int HW, int start)
{
    __shared__ float ts[32][33];
    __shared__ float tp[32][33];
    const int b   = blockIdx.z;
    const int d0  = blockIdx.y * 32;
    const int hw0 = blockIdx.x * 32;
    const int t   = threadIdx.x;
    const int hwl = t & 31;
    const int dl  = t >> 5;
#pragma unroll
    for (int p = 0; p < 4; ++p) {
        const int dd = dl + p * 8;
        const int d  = d0 + dd;
        const long idx = ((long)(b * DMODEL + d)) * HW + hw0 + hwl;
        ts[dd][hwl] = src[idx];
        tp[dd][hwl] = pos[idx] + le_row[d];
    }
    __syncthreads();
    const int dl2  = t & 31;
    const int hwl2 = t >> 5;
#pragma unroll
    for (int p = 0; p < 4; ++p) {
        const int hh  = hwl2 + p * 8;
        const int tok = start + hw0 + hh;
        const long o  = ((long)(b * STOT + tok)) * DMODEL + d0 + dl2;
        const float v = ts[dl2][hh];
        const float pp = tp[dl2][hh];
        out[o]  = v;
        outb[o] = f2bf(v);
        posb[o] = f2bf(pp);
        qb[o]   = f2bf(v + pp);
    }
}

// ---------------------------------------------------------------------------
// bf16 MFMA GEMM: Cb[M,N]bf16 = A[M,K]bf16 @ Bt[N,K]bf16^T + bias (relu opt)
// Double-buffered global_load_lds pipeline (R6 proven config). Optional
// second problem fused along grid.x (block-uniform pointer select).
// ---------------------------------------------------------------------------
__global__ __launch_bounds__(256)
void mfma_gemm(const u16* __restrict__ A, const u16* __restrict__ Bt,
               const int ldb, const float* __restrict__ bias,
               u16* __restrict__ Cb, const int ldc, u16* __restrict__ Cb2,
               const int K, const int relu,
               const u16* __restrict__ A1, const u16* __restrict__ Bt1,
               const float* __restrict__ bias1, u16* __restrict__ Cb1,
               u16* __restrict__ Cb21, const int nsplit)
{
    __shared__ u16 As[2][128 * 32];
    __shared__ u16 Bs[2][128 * 32];
    int bx = blockIdx.x;
    if (A1 && bx >= nsplit) {
        A = A1; Bt = Bt1; bias = bias1; Cb = Cb1; Cb2 = Cb21; bx -= nsplit;
    }
    const int tid  = threadIdx.x;
    const int wv   = tid >> 6;
    const int lane = tid & 63;
    const int m0 = blockIdx.y * 128;
    const int n0 = bx * 128;
    const int wm = (wv & 1) * 64;
    const int wn = (wv >> 1) * 64;
    const int q   = lane >> 4;
    const int c16 = lane & 15;

    // staging: chunk = it*4 + wv covers rows [chunk*16, chunk*16+16)
    const int lrow = lane >> 2;
    const int lcol = (lane & 3) * 8;   // u16 units

    const u16* ag[2];
    const u16* bg[2];
#pragma unroll
    for (int it = 0; it < 2; ++it) {
        const int chunk = it * 4 + wv;
        const int row = chunk * 16 + lrow;
        ag[it] = A  + (long)(m0 + row) * K   + lcol;
        bg[it] = Bt + (long)(n0 + row) * ldb + lcol;
    }

#define STAGE(buf, kk)                                          \
    {                                                           \
        _Pragma("unroll")                                       \
        for (int it = 0; it < 2; ++it) {                        \
            const int chunk = it * 4 + wv;                      \
            gload16(ag[it] + (kk), &As[buf][chunk * 512]);      \
            gload16(bg[it] + (kk), &Bs[buf][chunk * 512]);      \
        }                                                       \
    }

    floatx4 acc[4][4];
#pragma unroll
    for (int i = 0; i < 4; ++i)
#pragma unroll
        for (int j = 0; j < 4; ++j)
            acc[i][j] = (floatx4){0.f, 0.f, 0.f, 0.f};

    STAGE(0, 0);
    __syncthreads();

    int cur = 0;
    for (int k0 = 0; k0 < K; k0 += 32) {
        const int nxt = k0 + 32;
        if (nxt < K) {
            if (cur) { STAGE(0, nxt); } else { STAGE(1, nxt); }
        }

        const u16* Ab = &As[cur][0];
        const u16* Bb = &Bs[cur][0];
        short8 af[4], bf[4];
#pragma unroll
        for (int i = 0; i < 4; ++i) {
            af[i] = *(const short8*)&Ab[(wm + i * 16 + c16) * 32 + q * 8];
            bf[i] = *(const short8*)&Bb[(wn + i * 16 + c16) * 32 + q * 8];
        }
#pragma unroll
        for (int i = 0; i < 4; ++i)
#pragma unroll
            for (int j = 0; j < 4; ++j)
                acc[i][j] = __builtin_amdgcn_mfma_f32_16x16x32_bf16(
                    af[i], bf[j], acc[i][j], 0, 0, 0);
        __syncthreads();
        cur ^= 1;
    }
#undef STAGE

    // output selection (block-uniform)
    u16* cb  = Cb;
    int ldcb = ldc, csub = 0;
    if (Cb2 && n0 >= 256) { cb = Cb2; ldcb = 128; csub = 256; }

#pragma unroll
    for (int i = 0; i < 4; ++i) {
#pragma unroll
        for (int j = 0; j < 4; ++j) {
            const int col = n0 + wn + j * 16 + c16;
            const float bv = bias ? bias[col] : 0.f;
#pragma unroll
            for (int r = 0; r < 4; ++r) {
                const int row = m0 + wm + i * 16 + q * 4 + r;
                float v = acc[i][j][r] + bv;
                if (relu) v = fmaxf(v, 0.f);
                cb[(long)row * ldcb + col - csub] = f2bf(v);
            }
        }
    }
}

// ---------------------------------------------------------------------------
// GEMM (N=256 full width) + fused residual-add + LayerNorm epilogue.
// C = A[M,K] @ Bt[256,K]^T + bias;  x = C + out;  out = LN(x)*gamma+beta
// writes out f32, outb bf16, and (if qb) qb = bf16(LN + posb).
// Tile: 64 rows x 256 cols per block (grid = MTOT/64 = 680), 4 waves each
// 32x128 (acc[2][8]). Staging: same 2-buffer global_load_lds pipeline.
// Row stats: per-wave 16-lane shfl reduce + cross-wave LDS exchange
// (reuses the A-staging LDS after the K-loop's final barrier).
// ---------------------------------------------------------------------------
__global__ __launch_bounds__(256, 3)
void gemmln_kernel(const u16* __restrict__ A, const u16* __restrict__ Bt,
                   const float* __restrict__ bias,
                   float* __restrict__ out, u16* __restrict__ outb,
                   u16* __restrict__ qb, const u16* __restrict__ posb,
                   const float* __restrict__ gamma, const float* __restrict__ beta,
                   const int K)
{
    __shared__ u16 As[2][64 * 32];     // 8 KB
    __shared__ u16 Bs[2][256 * 32];    // 32 KB
    const int tid  = threadIdx.x;
    const int wv   = tid >> 6;
    const int lane = tid & 63;
    const int m0 = blockIdx.x * 64;
    const int wm  = (wv & 1) * 32;     // row offset within tile
    const int wn  = (wv >> 1) * 128;   // col offset
    const int q   = lane >> 4;
    const int c16 = lane & 15;

    const int lrow = lane >> 2;
    const int lcol = (lane & 3) * 8;   // u16 units

    const u16* ag = A + (long)(m0 + wv * 16 + lrow) * K + lcol;
    const u16* bg[4];
#pragma unroll
    for (int p = 0; p < 4; ++p)
        bg[p] = Bt + (long)(p * 64 + wv * 16 + lrow) * K + lcol;

#define STAGE(buf, kk)                                              \
    {                                                               \
        gload16(ag + (kk), &As[buf][(wv * 16) * 32]);               \
        _Pragma("unroll")                                           \
        for (int p = 0; p < 4; ++p)                                 \
            gload16(bg[p] + (kk), &Bs[buf][(p * 64 + wv * 16) * 32]); \
    }

    floatx4 acc[2][8];
#pragma unroll
    for (int i = 0; i < 2; ++i)
#pragma unroll
        for (int j = 0; j < 8; ++j)
            acc[i][j] = (floatx4){0.f, 0.f, 0.f, 0.f};

    STAGE(0, 0);
    __syncthreads();

    int cur = 0;
    for (int k0 = 0; k0 < K; k0 += 32) {
        const int nxt = k0 + 32;
        if (nxt < K) {
            if (cur) { STAGE(0, nxt); } else { STAGE(1, nxt); }
        }

        const u16* Ab = &As[cur][0];
        const u16* Bb = &Bs[cur][0];
        short8 af[2], bf[8];
#pragma unroll
        for (int i = 0; i < 2; ++i)
            af[i] = *(const short8*)&Ab[(wm + i * 16 + c16) * 32 + q * 8];
#pragma unroll
        for (int j = 0; j < 8; ++j)
            bf[j] = *(const short8*)&Bb[(wn + j * 16 + c16) * 32 + q * 8];
#pragma unroll
        for (int i = 0; i < 2; ++i)
#pragma unroll
            for (int j = 0; j < 8; ++j)
                acc[i][j] = __builtin_amdgcn_mfma_f32_16x16x32_bf16(
                    af[i], bf[j], acc[i][j], 0, 0, 0);
        __syncthreads();
        cur ^= 1;
    }
#undef STAGE

    // ---- epilogue: x = acc + bias + out; LN over each full row ----
    float bc[8], gc[8], ec[8];
#pragma unroll
    for (int j = 0; j < 8; ++j) {
        const int c = wn + j * 16 + c16;
        bc[j] = bias[c];
        gc[j] = gamma[c];
        ec[j] = beta[c];
    }

    // x (in place in acc) and per-row partial sums
    float s1[2][4], s2[2][4];
#pragma unroll
    for (int i = 0; i < 2; ++i) {
#pragma unroll
        for (int r = 0; r < 4; ++r) {
            const long token = (long)m0 + wm + i * 16 + q * 4 + r;
            const float* op = out + token * DMODEL;
            float a = 0.f, b2 = 0.f;
#pragma unroll
            for (int j = 0; j < 8; ++j) {
                float v = acc[i][j][r] + bc[j] + op[wn + j * 16 + c16];
                acc[i][j][r] = v;
                a += v;
                b2 = fmaf(v, v, b2);
            }
#pragma unroll
            for (int o = 1; o <= 8; o <<= 1) {
                a  += __shfl_xor(a, o);
                b2 += __shfl_xor(b2, o);
            }
            s1[i][r] = a;
            s2[i][r] = b2;
        }
    }

    // cross-wave exchange: red[row][half*2 + {0,1}] ; reuse As LDS (1 KB)
    float* red = (float*)&As[0][0];
    if (c16 == 0) {
        const int half = wn >> 7;   // 0 or 1
#pragma unroll
        for (int i = 0; i < 2; ++i)
#pragma unroll
            for (int r = 0; r < 4; ++r) {
                const int rl = wm + i * 16 + q * 4 + r;
                float2v v; v.x = s1[i][r]; v.y = s2[i][r];
                *(float2v*)&red[rl * 4 + half * 2] = v;
            }
    }
    __syncthreads();

    float mean[2][4], rstd[2][4];
#pragma unroll
    for (int i = 0; i < 2; ++i)
#pragma unroll
        for (int r = 0; r < 4; ++r) {
            const int rl = wm + i * 16 + q * 4 + r;
            const float4 v = *(const float4*)&red[rl * 4];
            const float m_  = (v.x + v.z) * (1.f / 256.f);
            const float e2  = (v.y + v.w) * (1.f / 256.f);
            const float var = fmaxf(e2 - m_ * m_, 0.f);
            mean[i][r] = m_;
            rstd[i][r] = rsqrtf(var + 1e-5f);
        }

#pragma unroll
    for (int i = 0; i < 2; ++i) {
#pragma unroll
        for (int r = 0; r < 4; ++r) {
            const long token = (long)m0 + wm + i * 16 + q * 4 + r;
            const float m_ = mean[i][r];
            const float rs = rstd[i][r];
            float* op  = out  + token * DMODEL;
            u16*   ob  = outb + token * DMODEL;
            u16*   qp  = qb   ? qb   + token * DMODEL : nullptr;
            const u16* pp = posb ? posb + token * DMODEL : nullptr;
#pragma unroll
            for (int j = 0; j < 8; ++j) {
                const int c = wn + j * 16 + c16;
                const float y = (acc[i][j][r] - m_) * rs * gc[j] + ec[j];
                op[c] = y;
                ob[c] = f2bf(y);
                if (qp) qp[c] = f2bf(y + bf2f(pp[c]));
            }
        }
    }
}

// ---------------------------------------------------------------------------
// Deformable sampling — hybrid decomposition, LDS-broadcast (w,o) table
// (R5 body: best measured config — occupancy-first, compiler-scheduled).
// ---------------------------------------------------------------------------
__device__ __forceinline__ void point_corners(
    float refx, float refy, unsigned int o2, float aP,
    int k, unsigned int base, float* w, unsigned int* o)
{
    const int lw = 128 >> k;
    const float flw = (float)lw;
    const float x = refx * flw - 0.5f + bf2f((u16)(o2 & 0xffffu));
    const float y = refy * flw - 0.5f + bf2f((u16)(o2 >> 16));
    const float x0f = floorf(x), y0f = floorf(y);
    const float lx = x - x0f, ly = y - y0f;
    const int x0 = (int)x0f, y0 = (int)y0f;
    const float wx0 = ((unsigned int)x0 < (unsigned int)lw) ? (1.f - lx) : 0.f;
    const float wx1 = ((unsigned int)(x0 + 1) < (unsigned int)lw) ? lx : 0.f;
    const float wy0 = ((unsigned int)y0 < (unsigned int)lw) ? (aP * (1.f - ly)) : 0.f;
    const float wy1 = ((unsigned int)(y0 + 1) < (unsigned int)lw) ? (aP * ly) : 0.f;
    // byte offsets: token stride 512B; row stride lw*512 = 1<<(16-k)
    const unsigned int xc0 = (unsigned int)(x0 & (lw - 1)) << 9;
    const unsigned int xc1 = (unsigned int)((x0 + 1) & (lw - 1)) << 9;
    const unsigned int r0 = (unsigned int)(y0 & (lw - 1)) << (16 - k);
    const unsigned int r1 = (unsigned int)((y0 + 1) & (lw - 1)) << (16 - k);
    w[0] = wy0 * wx0; o[0] = base + r0 + xc0;
    w[1] = wy0 * wx1; o[1] = base + r0 + xc1;
    w[2] = wy1 * wx0; o[2] = base + r1 + xc0;
    w[3] = wy1 * wx1; o[3] = base + r1 + xc1;
}

__global__ __launch_bounds__(256, 4)
void sample_kernel(const u16* __restrict__ value, const u16* __restrict__ offb,
                   const u16* __restrict__ logit, u16* __restrict__ sb)
{
    // per wave: 8 heads x 132 uints (512B payload + 16B pad) = 4224B
    __shared__ unsigned int pwtab[4 * 8 * 132];

    const int t  = threadIdx.x;
    const int wv = t >> 6;                 // token slot within block
    const int l  = t & 63;
    const int h  = l >> 3;                 // head 0..7
    const int u  = l & 7;                  // point-pair owner / channel slice
    const int blk = blockIdx.x * 4 + wv;   // global token
    const int b = blk / STOT;
    const int s = blk - b * STOT;

    float refx, refy;
    if (s < 16384) {
        const int yy = s >> 7, xx = s & 127;
        refx = (xx + 0.5f) * (1.f / 128.f); refy = (yy + 0.5f) * (1.f / 128.f);
    } else if (s < 20480) {
        const int sl = s - 16384; const int yy = sl >> 6, xx = sl & 63;
        refx = (xx + 0.5f) * (1.f / 64.f);  refy = (yy + 0.5f) * (1.f / 64.f);
    } else if (s < 21504) {
        const int sl = s - 20480; const int yy = sl >> 5, xx = sl & 31;
        refx = (xx + 0.5f) * (1.f / 32.f);  refy = (yy + 0.5f) * (1.f / 32.f);
    } else {
        const int sl = s - 21504; const int yy = sl >> 4, xx = sl & 15;
        refx = (xx + 0.5f) * (1.f / 16.f);  refy = (yy + 0.5f) * (1.f / 16.f);
    }

    // ---- phase 1: this lane's 2 points ----
    const unsigned int* offp = (const unsigned int*)(offb + (long)blk * 256 + h * 32);
    const unsigned int o2_0 = offp[u];
    const unsigned int o2_1 = offp[u + 8];
    const u16* lp = logit + (long)blk * 128 + h * 16;
    const float l0 = bf2f(lp[u]);
    const float l1 = bf2f(lp[u + 8]);

    // softmax across the head's 8 lanes (16 logits)
    float m = fmaxf(l0, l1);
    m = fmaxf(m, __shfl_xor(m, 1));
    m = fmaxf(m, __shfl_xor(m, 2));
    m = fmaxf(m, __shfl_xor(m, 4));
    const float e0 = __expf(l0 - m);
    const float e1 = __expf(l1 - m);
    float se = e0 + e1;
    se += __shfl_xor(se, 1);
    se += __shfl_xor(se, 2);
    se += __shfl_xor(se, 4);
    const float inv = 1.f / se;
    const float aP0 = e0 * inv;
    const float aP1 = e1 * inv;

    // levels: point u -> level u>>2 (0/1), point u+8 -> level (u>>2)+2 (2/3)
    const int k0 = u >> 2;
    const unsigned int LS0 = k0 ? 16384u : 0u;
    const unsigned int LS1 = k0 ? 21504u : 20480u;
    const unsigned int tb = (unsigned int)(b * STOT);
    const unsigned int hb64 = (unsigned int)(h * 64);
    const unsigned int base0 = (tb + LS0) * 512u + hb64;
    const unsigned int base1 = (tb + LS1) * 512u + hb64;

    float ww[8];
    unsigned int oo[8];
    point_corners(refx, refy, o2_0, aP0, k0,     base0, ww,     oo);
    point_corners(refx, refy, o2_1, aP1, k0 + 2, base1, ww + 4, oo + 4);

    // ---- publish (w,o) pairs to the per-head LDS table ----
    unsigned int* wbase = pwtab + (wv * 8 + h) * 132;
    {
        uint4 p0, p1, p2, p3;
        p0.x = __float_as_uint(ww[0]); p0.y = oo[0];
        p0.z = __float_as_uint(ww[1]); p0.w = oo[1];
        p1.x = __float_as_uint(ww[2]); p1.y = oo[2];
        p1.z = __float_as_uint(ww[3]); p1.w = oo[3];
        p2.x = __float_as_uint(ww[4]); p2.y = oo[4];
        p2.z = __float_as_uint(ww[5]); p2.w = oo[5];
        p3.x = __float_as_uint(ww[6]); p3.y = oo[6];
        p3.z = __float_as_uint(ww[7]); p3.w = oo[7];
        *(uint4*)(wbase + u * 8)           = p0;
        *(uint4*)(wbase + u * 8 + 4)       = p1;
        *(uint4*)(wbase + (u + 8) * 8)     = p2;
        *(uint4*)(wbase + (u + 8) * 8 + 4) = p3;
    }
    __builtin_amdgcn_wave_barrier();   // same-wave producer/consumer only

    // ---- phase 2: coalesced gathers, 4 points per batch ----
    const unsigned int chb = (unsigned int)(u * 8);  // channel byte offset
    const char* vp = (const char*)value;
    float2v acc0; acc0.x = 0.f; acc0.y = 0.f;
    float2v acc1; acc1.x = 0.f; acc1.y = 0.f;

#pragma unroll
    for (int g = 0; g < 4; ++g) {
        const uint4* gp = (const uint4*)(wbase + g * 32);
        uint4 qq[8];
#pragma unroll
        for (int i = 0; i < 8; ++i) qq[i] = gp[i];
        uint2 dB[16];
#pragma unroll
        for (int i = 0; i < 8; ++i) {
            dB[2 * i]     = *(const uint2*)(vp + (qq[i].y + chb));
            dB[2 * i + 1] = *(const uint2*)(vp + (qq[i].w + chb));
        }
#pragma unroll
        for (int i = 0; i < 8; ++i) {
            float2v wa; wa.x = __uint_as_float(qq[i].x); wa.y = wa.x;
            pkfma(acc0, wa, unpk(dB[2 * i].x));
            pkfma(acc1, wa, unpk(dB[2 * i].y));
            float2v wb; wb.x = __uint_as_float(qq[i].z); wb.y = wb.x;
            pkfma(acc0, wb, unpk(dB[2 * i + 1].x));
            pkfma(acc1, wb, unpk(dB[2 * i + 1].y));
        }
    }

    ushort4 r;
    r.x = f2bf(acc0.x); r.y = f2bf(acc0.y);
    r.z = f2bf(acc1.x); r.w = f2bf(acc1.y);
    *(ushort4*)(sb + (long)blk * DMODEL + h * 32 + u * 4) = r;
}

// ---------------------------------------------------------------------------
extern "C" void kernel_launch(void* const* d_in, const int* in_sizes, int n_in,
                              void* d_out, int out_size, void* d_ws, size_t ws_size,
                              hipStream_t stream)
{
    const float* src[4] = {(const float*)d_in[0], (const float*)d_in[2],
                           (const float*)d_in[4], (const float*)d_in[6]};
    const float* pos[4] = {(const float*)d_in[1], (const float*)d_in[3],
                           (const float*)d_in[5], (const float*)d_in[7]};
    const float* level_embed = (const float*)d_in[8];
    const float* Woff  = (const float*)d_in[9];
    const float* boff  = (const float*)d_in[10];
    const float* Wattn = (const float*)d_in[11];
    const float* battn = (const float*)d_in[12];
    const float* Wval  = (const float*)d_in[13];
    const float* bval  = (const float*)d_in[14];
    const float* Wout  = (const float*)d_in[15];
    const float* bout  = (const float*)d_in[16];
    const float* ln1s  = (const float*)d_in[17];
    const float* ln1b  = (const float*)d_in[18];
    const float* W1    = (const float*)d_in[19];
    const float* b1    = (const float*)d_in[20];
    const float* W2    = (const float*)d_in[21];
    const float* b2    = (const float*)d_in[22];
    const float* ln2s  = (const float*)d_in[23];
    const float* ln2b  = (const float*)d_in[24];

    float* out = (float*)d_out;                       // residual stream f32
    const long MD = (long)MTOT * DMODEL;              // 11,141,120

    // workspace layout (~187 MB)
    u16* outb = (u16*)d_ws;          // [M,256] LN output bf16
    u16* posb = outb + MD;           // [M,256] pos_flat bf16
    u16* qb   = posb + MD;           // [M,256] q = out+pos bf16
    u16* db   = qb + MD;             // [M,256] (unused now, kept for layout)
    u16* vb   = db + MD;             // [M,256] value bf16      (hb region start)
    u16* offb = vb + MD;             // [M,256] offsets bf16
    u16* awb  = offb + MD;           // [M,128] attn logits bf16
    u16* sb   = awb + MD / 2;        // [M,256] sampled bf16
    u16* hb   = vb;                  // [M,1024] FF hidden (aliases vb..sb+pad)
    u16* wts  = vb + 4 * MD;         // bf16 transposed weights
    u16* Wvalt = wts;
    u16* Wofat = Wvalt + 6L * 256 * 256;   // [384,256] per layer: Woff^T||Wattn^T
    u16* Woutt = Wofat + 6L * 384 * 256;
    u16* W1t   = Woutt + 6L * 256 * 256;
    u16* W2t   = W1t   + 6L * 1024 * 256;
    float* bias384 = (float*)(W2t + 6L * 1024 * 256);  // [NLAY][384]

    // ---- weight prep (every call; ~9 MB) ----
    biascat_kernel<<<9, 256, 0, stream>>>(boff, battn, bias384);
    wtrans_kernel<<<dim3(8, 8, 6),  256, 0, stream>>>(Wval,  Wvalt, 256, 256,
                                                      65536, 65536);
    wtrans_kernel<<<dim3(8, 8, 6),  256, 0, stream>>>(Woff,  Wofat, 256, 256,
                                                      65536, 98304);
    wtrans_kernel<<<dim3(4, 8, 6),  256, 0, stream>>>(Wattn, Wofat + 256 * 256,
                                                      256, 128, 32768, 98304);
    wtrans_kernel<<<dim3(8, 8, 6),  256, 0, stream>>>(Wout,  Woutt, 256, 256,
                                                      65536, 65536);
    wtrans_kernel<<<dim3(32, 8, 6), 256, 0, stream>>>(W1,    W1t, 256, 1024,
                                                      262144, 262144);
    wtrans_kernel<<<dim3(8, 32, 6), 256, 0, stream>>>(W2,    W2t, 1024, 256,
                                                      262144, 262144);

    // ---- flatten ----
    {
        const int HW[4] = {16384, 4096, 1024, 256};
        const int ST[4] = {0, 16384, 20480, 21504};
        for (int l = 0; l < 4; ++l) {
            dim3 g(HW[l] / 32, DMODEL / 32, NB);
            flatten_kernel<<<g, 256, 0, stream>>>(src[l], pos[l],
                                                  level_embed + l * DMODEL,
                                                  out, outb, posb, qb, HW[l], ST[l]);
        }
    }

    const dim3 g5(5, MTOT / 128);   // merged value (2) + off/attn (3)
    const dim3 g8(8, MTOT / 128);   // N=1024 (FF1)

    for (int i = 0; i < NLAY; ++i) {
        const u16* Wv  = Wvalt + (long)i * 256 * 256;
        const u16* Wqa = Wofat + (long)i * 384 * 256;
        const u16* Wou = Woutt + (long)i * 256 * 256;
        const u16* W1i = W1t   + (long)i * 1024 * 256;
        const u16* W2i = W2t   + (long)i * 256 * 1024;
        const float* bv  = bval + (long)i * 256;
        const float* bqa = bias384 + (long)i * 384;
        const float* bou = bout + (long)i * 256;
        const float* b1i = b1   + (long)i * DFF;
        const float* b2i = b2   + (long)i * 256;

        // merged: value = outb @ Wval + bval -> vb  (blocks 0..1)
        //         [off|attn] = qb @ Wqa + bqa -> offb/awb (blocks 2..4)
        mfma_gemm<<<g5, 256, 0, stream>>>(outb, Wv, 256, bv,
                                          vb, 256, nullptr, 256, 0,
                                          qb, Wqa, bqa, offb, awb, 2);
        // sampling with fused softmax (reads logits directly)
        sample_kernel<<<MTOT / 4, 256, 0, stream>>>(vb, offb, awb, sb);
        // attn_out GEMM + residual + LN1 fused -> out/outb
        gemmln_kernel<<<MTOT / 64, 256, 0, stream>>>(sb, Wou, bou,
                                                     out, outb, nullptr, nullptr,
                                                     ln1s + (long)i * 256,
                                                     ln1b + (long)i * 256, 256);
        // FF: h = relu(out @ W1 + b1) -> hb bf16 [M,1024]
        mfma_gemm<<<g8, 256, 0, stream>>>(outb, W1i, 256, b1i,
                                          hb, 1024, nullptr, 256, 1,
                                          nullptr, nullptr, nullptr, nullptr,
                                          nullptr, 0);
        // FF2 GEMM + residual + LN2 fused -> out/outb/qb
        gemmln_kernel<<<MTOT / 64, 256, 0, stream>>>(hb, W2i, b2i,
                                                     out, outb, qb, posb,
                                                     ln2s + (long)i * 256,
                                                     ln2b + (long)i * 256, 1024);
    }
}